// Round 7
// baseline (255.600 us; speedup 1.0000x reference)
//
#include <hip/hip_runtime.h>

// LightGCN: out = 0.25*(h0 + h1 + h2 + h3), h_{k+1} = A_w · h_k.
// Embeddings converted to bf16 once (the one mandatory f32 read) -> whole
// gather working set (E, h1, h2, pe ~ 202 MB) is L3-resident.
// CSR-by-dst via two-level partition (L2-local scatter). f32 accumulate.

#define USER_NUM  300000
#define ITEM_NUM  200000
#define N_NODES   500000
#define EMBED_DIM 64
#define N_EDGES   1250000
#define NV   (N_NODES * EMBED_DIM)   // 32,000,000 floats
#define NV4  (NV / 4)

#define BSHIFT  11
#define BNODES  2048                               // nodes per coarse bucket
#define NBUK    ((N_NODES + BNODES - 1) / BNODES)  // 245
#define PCHUNK  4096                               // edges per partition block
#define PGRID   ((N_EDGES + PCHUNK - 1) / PCHUNK)  // 306

// ---------------- bf16 helpers (storage only; math in f32) ----------------
__device__ __forceinline__ unsigned bpack(float lo, float hi) {
    unsigned a = __float_as_uint(lo), b = __float_as_uint(hi);
    a = (a + 0x7fffu + ((a >> 16) & 1u)) >> 16;          // RN-to-even
    b = (b + 0x7fffu + ((b >> 16) & 1u)) & 0xffff0000u;
    return a | b;
}
__device__ __forceinline__ float blo(unsigned u) { return __uint_as_float(u << 16); }
__device__ __forceinline__ float bhi(unsigned u) { return __uint_as_float(u & 0xffff0000u); }

__device__ __forceinline__ void bf8_fma(uint4 g, float w, float* a) {
    a[0] += w * blo(g.x); a[1] += w * bhi(g.x);
    a[2] += w * blo(g.y); a[3] += w * bhi(g.y);
    a[4] += w * blo(g.z); a[5] += w * bhi(g.z);
    a[6] += w * blo(g.w); a[7] += w * bhi(g.w);
}

// ---------------- emb f32 -> bf16 (streaming, once) ----------------
__global__ void conv_kernel(const float4* __restrict__ ue,
                            const float4* __restrict__ ie,
                            uint4* __restrict__ E) {
    int i = blockIdx.x * blockDim.x + threadIdx.x;   // [0, N_NODES*8)
    if (i >= N_NODES * 8) return;
    int n = i >> 3, sub = i & 7;
    const float4* p = (n < USER_NUM) ? &ue[(size_t)n * 16]
                                     : &ie[(size_t)(n - USER_NUM) * 16];
    float4 a = p[sub * 2], b = p[sub * 2 + 1];
    uint4 r;
    r.x = bpack(a.x, a.y); r.y = bpack(a.z, a.w);
    r.z = bpack(b.x, b.y); r.w = bpack(b.z, b.w);
    E[i] = r;
}

// ---------------- CSR build: two-level partition ----------------
__global__ void bhist_kernel(const int* __restrict__ dst, int* __restrict__ bcnt) {
    __shared__ int h[256];
    int t = threadIdx.x;
    h[t] = 0;
    __syncthreads();
    int cbase = blockIdx.x * PCHUNK;
    int cnt = min(PCHUNK, N_EDGES - cbase);
    for (int i = t; i < cnt; i += 256)
        atomicAdd(&h[dst[cbase + i] >> BSHIFT], 1);
    __syncthreads();
    if (t < NBUK && h[t]) atomicAdd(&bcnt[t], h[t]);
}

__global__ void bscan_kernel(const int* __restrict__ bcnt,
                             int* __restrict__ boff,
                             int* __restrict__ bcur,
                             int* __restrict__ offs) {
    __shared__ int lds[256];
    int t = threadIdx.x;
    int v = (t < NBUK) ? bcnt[t] : 0;
    lds[t] = v;
    __syncthreads();
    for (int off = 1; off < 256; off <<= 1) {
        int x = (t >= off) ? lds[t - off] : 0;
        __syncthreads();
        if (t >= off) lds[t] += x;
        __syncthreads();
    }
    int excl = lds[t] - v;
    if (t < NBUK) { boff[t] = excl; bcur[t] = excl; }
    if (t == NBUK - 1) boff[NBUK] = N_EDGES;
    if (t == 0) offs[N_NODES] = N_EDGES;
}

// tmp entry: int2{ (ldst<<19)|src , float_bits(w) }  (src<2^19, ldst<2^11)
__global__ void part_kernel(const int* __restrict__ src,
                            const int* __restrict__ dst,
                            const float* __restrict__ w,
                            int* __restrict__ bcur,
                            int2* __restrict__ tmp) {
    __shared__ int hist[256];
    __shared__ int base[256];
    int t = threadIdx.x;
    int cbase = blockIdx.x * PCHUNK;
    int cnt = min(PCHUNK, N_EDGES - cbase);
    int key[16], eb[16];
    float ew[16];
    hist[t] = 0;
    __syncthreads();
    #pragma unroll
    for (int k = 0; k < 16; ++k) {
        int i = t + k * 256;
        if (i < cnt) {
            int e = cbase + i;
            int d = dst[e];
            eb[k]  = d >> BSHIFT;
            key[k] = ((d & (BNODES - 1)) << 19) | src[e];
            ew[k]  = w[e];
            atomicAdd(&hist[eb[k]], 1);
        } else eb[k] = -1;
    }
    __syncthreads();
    int h = hist[t];
    base[t] = (h > 0) ? atomicAdd(&bcur[t], h) : 0;
    __syncthreads();
    hist[t] = 0;                     // reuse as local cursor
    __syncthreads();
    #pragma unroll
    for (int k = 0; k < 16; ++k) {
        if (eb[k] >= 0) {
            int r = atomicAdd(&hist[eb[k]], 1);
            tmp[base[eb[k]] + r] = make_int2(key[k], __float_as_int(ew[k]));
        }
    }
}

__global__ void fine_kernel(const int2* __restrict__ tmp,
                            const int* __restrict__ boff,
                            int* __restrict__ offs,
                            int2* __restrict__ pe) {
    __shared__ int cnt[BNODES];
    __shared__ int sums[256];
    int b = blockIdx.x, t = threadIdx.x;
    int nbase = b << BSHIFT;
    int ebeg = boff[b], eend = boff[b + 1];
    for (int j = t; j < BNODES; j += 256) cnt[j] = 0;
    __syncthreads();
    for (int i = ebeg + t; i < eend; i += 256)
        atomicAdd(&cnt[((unsigned)tmp[i].x) >> 19], 1);
    __syncthreads();
    int s[8], tot = 0;
    #pragma unroll
    for (int k = 0; k < 8; ++k) { s[k] = cnt[t * 8 + k]; tot += s[k]; }
    sums[t] = tot;
    __syncthreads();
    for (int off = 1; off < 256; off <<= 1) {
        int x = (t >= off) ? sums[t - off] : 0;
        __syncthreads();
        if (t >= off) sums[t] += x;
        __syncthreads();
    }
    int run = ebeg + sums[t] - tot;
    #pragma unroll
    for (int k = 0; k < 8; ++k) {
        int node = nbase + t * 8 + k;
        if (node < N_NODES) offs[node] = run;
        cnt[t * 8 + k] = run;        // cursor
        run += s[k];
    }
    __syncthreads();
    for (int i = ebeg + t; i < eend; i += 256) {
        int2 E2 = tmp[i];
        int p = atomicAdd(&cnt[((unsigned)E2.x) >> 19], 1);
        pe[p] = make_int2(E2.x & 0x7FFFF, E2.y);
    }
}

// ------------- layer: gather bf16 -> bf16 (8 lanes/node, 8 nodes/wave) ----
__global__ void layer_kernel(const uint4* __restrict__ hsrc,
                             uint4* __restrict__ hout,
                             const int* __restrict__ offs,
                             const int2* __restrict__ pe) {
    int gid  = blockIdx.x * blockDim.x + threadIdx.x;
    int wave = gid >> 6;
    int lane = gid & 63;
    int grp  = lane >> 3;
    int sub  = lane & 7;
    int n    = wave * 8 + grp;
    if (n >= N_NODES) return;
    int beg = offs[n], end = offs[n + 1];
    float a0[8] = {0,0,0,0,0,0,0,0};
    float a1[8] = {0,0,0,0,0,0,0,0};
    int e = beg;
    for (; e + 2 <= end; e += 2) {
        int2 p0 = pe[e], p1 = pe[e + 1];
        uint4 g0 = hsrc[(size_t)p0.x * 8 + sub];
        uint4 g1 = hsrc[(size_t)p1.x * 8 + sub];
        bf8_fma(g0, __int_as_float(p0.y), a0);
        bf8_fma(g1, __int_as_float(p1.y), a1);
    }
    if (e < end) {
        int2 p0 = pe[e];
        uint4 g0 = hsrc[(size_t)p0.x * 8 + sub];
        bf8_fma(g0, __int_as_float(p0.y), a0);
    }
    #pragma unroll
    for (int i = 0; i < 8; ++i) a0[i] += a1[i];
    uint4 r;
    r.x = bpack(a0[0], a0[1]); r.y = bpack(a0[2], a0[3]);
    r.z = bpack(a0[4], a0[5]); r.w = bpack(a0[6], a0[7]);
    hout[(size_t)n * 8 + sub] = r;
}

// final: gather h3 from h2; out = 0.25*(E + h1 + h2 + h3), f32 out
__global__ void final_kernel(const uint4* __restrict__ E,
                             const uint4* __restrict__ h1,
                             const uint4* __restrict__ h2,
                             float4* __restrict__ out,
                             const int* __restrict__ offs,
                             const int2* __restrict__ pe) {
    int gid  = blockIdx.x * blockDim.x + threadIdx.x;
    int wave = gid >> 6;
    int lane = gid & 63;
    int grp  = lane >> 3;
    int sub  = lane & 7;
    int n    = wave * 8 + grp;
    if (n >= N_NODES) return;
    int beg = offs[n], end = offs[n + 1];
    float a0[8] = {0,0,0,0,0,0,0,0};
    float a1[8] = {0,0,0,0,0,0,0,0};
    int e = beg;
    for (; e + 2 <= end; e += 2) {
        int2 p0 = pe[e], p1 = pe[e + 1];
        uint4 g0 = h2[(size_t)p0.x * 8 + sub];
        uint4 g1 = h2[(size_t)p1.x * 8 + sub];
        bf8_fma(g0, __int_as_float(p0.y), a0);
        bf8_fma(g1, __int_as_float(p1.y), a1);
    }
    if (e < end) {
        int2 p0 = pe[e];
        uint4 g0 = h2[(size_t)p0.x * 8 + sub];
        bf8_fma(g0, __int_as_float(p0.y), a0);
    }
    size_t o8 = (size_t)n * 8 + sub;
    uint4 e0 = E[o8], b1 = h1[o8], b2 = h2[o8];
    float4 ra, rb;
    ra.x = 0.25f * (blo(e0.x) + blo(b1.x) + blo(b2.x) + a0[0] + a1[0]);
    ra.y = 0.25f * (bhi(e0.x) + bhi(b1.x) + bhi(b2.x) + a0[1] + a1[1]);
    ra.z = 0.25f * (blo(e0.y) + blo(b1.y) + blo(b2.y) + a0[2] + a1[2]);
    ra.w = 0.25f * (bhi(e0.y) + bhi(b1.y) + bhi(b2.y) + a0[3] + a1[3]);
    rb.x = 0.25f * (blo(e0.z) + blo(b1.z) + blo(b2.z) + a0[4] + a1[4]);
    rb.y = 0.25f * (bhi(e0.z) + bhi(b1.z) + bhi(b2.z) + a0[5] + a1[5]);
    rb.z = 0.25f * (blo(e0.w) + blo(b1.w) + blo(b2.w) + a0[6] + a1[6]);
    rb.w = 0.25f * (bhi(e0.w) + bhi(b1.w) + bhi(b2.w) + a0[7] + a1[7]);
    out[(size_t)n * 16 + sub * 2]     = ra;
    out[(size_t)n * 16 + sub * 2 + 1] = rb;
}

// ---------------- fallback (round-1 atomic) path ----------------
__global__ void init_fb_kernel(const float4* __restrict__ ue,
                               const float4* __restrict__ ie,
                               float4* __restrict__ h,
                               float4* __restrict__ hn,
                               float4* __restrict__ acc) {
    int i = blockIdx.x * blockDim.x + threadIdx.x;
    if (i >= NV4) return;
    const int ub = USER_NUM * EMBED_DIM / 4;
    float4 v = (i < ub) ? ue[i] : ie[i - ub];
    h[i] = v; acc[i] = v;
    hn[i] = make_float4(0.f, 0.f, 0.f, 0.f);
}

__global__ void spmm_fb_kernel(const float* __restrict__ h, float* __restrict__ hn,
                               const int* __restrict__ src, const int* __restrict__ dst,
                               const float* __restrict__ w) {
    int gid = blockIdx.x * blockDim.x + threadIdx.x;
    int wave = gid >> 6, lane = gid & 63;
    int nwave = (gridDim.x * blockDim.x) >> 6;
    for (int e = wave; e < N_EDGES; e += nwave) {
        float v = h[src[e] * 64 + lane] * w[e];
        atomicAdd(&hn[dst[e] * 64 + lane], v);
    }
}

template <int LAST>
__global__ void accum_fb_kernel(float4* __restrict__ acc, const float4* __restrict__ hn,
                                float4* __restrict__ zbuf) {
    int i = blockIdx.x * blockDim.x + threadIdx.x;
    if (i >= NV4) return;
    float4 a = acc[i], n = hn[i];
    a.x += n.x; a.y += n.y; a.z += n.z; a.w += n.w;
    if (LAST) { a.x *= 0.25f; a.y *= 0.25f; a.z *= 0.25f; a.w *= 0.25f; }
    acc[i] = a;
    if (!LAST) zbuf[i] = make_float4(0.f, 0.f, 0.f, 0.f);
}

extern "C" void kernel_launch(void* const* d_in, const int* in_sizes, int n_in,
                              void* d_out, int out_size, void* d_ws, size_t ws_size,
                              hipStream_t stream) {
    const float* ue  = (const float*)d_in[0];
    const float* ie  = (const float*)d_in[1];
    const float* w   = (const float*)d_in[2];
    const int*   src = (const int*)d_in[3];
    const int*   dst = (const int*)d_in[4];

    float* out = (float*)d_out;

    // workspace: E(64MB), B=h1(64MB), C=h2(64MB), tmp(int2 10MB),
    //            pe(int2 10MB), offs, boff, bcnt, bcur
    const size_t HB = (size_t)N_NODES * 128;
    char*  base = (char*)d_ws;
    uint4* E    = (uint4*)base;
    uint4* B    = (uint4*)(base + HB);
    uint4* C    = (uint4*)(base + 2 * HB);
    int2*  tmp  = (int2*)(base + 3 * HB);                   // N_EDGES
    int2*  pe   = (int2*)(base + 3 * HB + (size_t)N_EDGES * 8);
    int*   offs = (int*)((char*)pe + (size_t)N_EDGES * 8);  // N_NODES+1
    int*   boff = offs + (N_NODES + 1);                     // NBUK+1
    int*   bcnt = boff + (NBUK + 1);                        // NBUK
    int*   bcur = bcnt + NBUK;                              // NBUK

    const size_t needed = 3 * HB + (size_t)N_EDGES * 16
                        + (size_t)(N_NODES + 1 + 3 * NBUK + 1) * 4;

    const int TB = 256;
    const int egrid = NV4 / TB;
    const int cgrid = (N_NODES * 8) / TB + 1;     // conv
    const int fgrid = (N_NODES / 8 * 64) / TB;    // 15625 (8 nodes/wave)

    if (ws_size >= needed) {
        // ---- CSR build (two-level partition) + emb conversion ----
        hipMemsetAsync(bcnt, 0, (size_t)NBUK * 4, stream);
        bhist_kernel<<<PGRID, TB, 0, stream>>>(dst, bcnt);
        bscan_kernel<<<1, 256, 0, stream>>>(bcnt, boff, bcur, offs);
        part_kernel<<<PGRID, TB, 0, stream>>>(src, dst, w, bcur, tmp);
        fine_kernel<<<NBUK, TB, 0, stream>>>(tmp, boff, offs, pe);
        conv_kernel<<<cgrid, TB, 0, stream>>>((const float4*)ue, (const float4*)ie, E);

        // ---- propagation ----
        layer_kernel<<<fgrid, TB, 0, stream>>>(E, B, offs, pe);   // h1
        layer_kernel<<<fgrid, TB, 0, stream>>>(B, C, offs, pe);   // h2
        final_kernel<<<fgrid, TB, 0, stream>>>(E, B, C, (float4*)out, offs, pe);
    } else {
        // ---- fallback: atomic path ----
        float* A  = (float*)d_ws;
        float* Bf = A + NV;
        const int sgrid = 4096;
        init_fb_kernel<<<egrid, TB, 0, stream>>>((const float4*)ue, (const float4*)ie,
                                                 (float4*)A, (float4*)Bf, (float4*)out);
        spmm_fb_kernel<<<sgrid, TB, 0, stream>>>(A, Bf, src, dst, w);
        accum_fb_kernel<0><<<egrid, TB, 0, stream>>>((float4*)out, (const float4*)Bf, (float4*)A);
        spmm_fb_kernel<<<sgrid, TB, 0, stream>>>(Bf, A, src, dst, w);
        accum_fb_kernel<0><<<egrid, TB, 0, stream>>>((float4*)out, (const float4*)A, (float4*)Bf);
        spmm_fb_kernel<<<sgrid, TB, 0, stream>>>(A, Bf, src, dst, w);
        accum_fb_kernel<1><<<egrid, TB, 0, stream>>>((float4*)out, (const float4*)Bf, nullptr);
    }
}

// Round 8
// 218.482 us; speedup vs baseline: 1.1699x; 1.1699x over previous
//
#include <hip/hip_runtime.h>

// LightGCN: out = 0.25*(h0 + h1 + h2 + h3), h_{k+1} = A_w · h_k.
// bf16 embeddings/intermediates (f32 accumulate) -> gather set L3-resident.
// CSR-by-dst via capacity-padded two-level partition (no bhist/bscan),
// conv fused into the partition kernel, nontemporal streams where read-once.

#define USER_NUM  300000
#define ITEM_NUM  200000
#define N_NODES   500000
#define EMBED_DIM 64
#define NV   (N_NODES * EMBED_DIM)
#define NV4  (NV / 4)
#define N_EDGES   1250000

#define BSHIFT  11
#define BNODES  2048                               // nodes per coarse bucket
#define NBUK    ((N_NODES + BNODES - 1) / BNODES)  // 245
#define CAP     8192                               // padded slots per bucket
#define PCHUNK  4096                               // edges per partition block
#define PGRID   ((N_EDGES + PCHUNK - 1) / PCHUNK)  // 306
#define CONVG   ((N_NODES * 8) / 256)              // 15625 conv blocks

typedef float    f32x4 __attribute__((ext_vector_type(4)));

// ---------------- bf16 helpers (storage only; math in f32) ----------------
__device__ __forceinline__ unsigned bpack(float lo, float hi) {
    unsigned a = __float_as_uint(lo), b = __float_as_uint(hi);
    a = (a + 0x7fffu + ((a >> 16) & 1u)) >> 16;          // RN-to-even
    b = (b + 0x7fffu + ((b >> 16) & 1u)) & 0xffff0000u;
    return a | b;
}
__device__ __forceinline__ float blo(unsigned u) { return __uint_as_float(u << 16); }
__device__ __forceinline__ float bhi(unsigned u) { return __uint_as_float(u & 0xffff0000u); }

__device__ __forceinline__ void bf8_fma(uint4 g, float w, float* a) {
    a[0] += w * blo(g.x); a[1] += w * bhi(g.x);
    a[2] += w * blo(g.y); a[3] += w * bhi(g.y);
    a[4] += w * blo(g.z); a[5] += w * bhi(g.z);
    a[6] += w * blo(g.w); a[7] += w * bhi(g.w);
}

// -------- fused pre-pass: blocks [0,PGRID) partition edges into padded
// buckets; blocks [PGRID, PGRID+CONVG) convert f32 emb -> bf16 E ----------
__global__ void pre_kernel(const int* __restrict__ src,
                           const int* __restrict__ dst,
                           const float* __restrict__ w,
                           int* __restrict__ bcur,
                           int2* __restrict__ tmp,
                           const float4* __restrict__ ue,
                           const float4* __restrict__ ie,
                           uint4* __restrict__ E) {
    __shared__ int hist[256];
    __shared__ int rbase[256];
    int t = threadIdx.x;
    if (blockIdx.x >= PGRID) {
        // ---- conv: stream f32 emb -> bf16 (nontemporal reads: read-once) ----
        int i = (blockIdx.x - PGRID) * 256 + t;          // [0, N_NODES*8)
        int n = i >> 3, sub = i & 7;
        const f32x4* p = (const f32x4*)((n < USER_NUM) ? &ue[(size_t)n * 16]
                                                       : &ie[(size_t)(n - USER_NUM) * 16]);
        f32x4 a = __builtin_nontemporal_load(&p[sub * 2]);
        f32x4 b = __builtin_nontemporal_load(&p[sub * 2 + 1]);
        uint4 r;
        r.x = bpack(a.x, a.y); r.y = bpack(a.z, a.w);
        r.z = bpack(b.x, b.y); r.w = bpack(b.z, b.w);
        E[i] = r;
        return;
    }
    // ---- partition: per-chunk LDS hist + one reservation per bucket ----
    int cbase = blockIdx.x * PCHUNK;
    int cnt = min(PCHUNK, N_EDGES - cbase);
    int key[16], eb[16];
    float ew[16];
    hist[t] = 0;
    __syncthreads();
    #pragma unroll
    for (int k = 0; k < 16; ++k) {
        int i = t + k * 256;
        if (i < cnt) {
            int e = cbase + i;
            int d = dst[e];
            eb[k]  = d >> BSHIFT;
            key[k] = ((d & (BNODES - 1)) << 19) | src[e];   // src < 2^19
            ew[k]  = w[e];
            atomicAdd(&hist[eb[k]], 1);
        } else eb[k] = -1;
    }
    __syncthreads();
    int h = hist[t];
    rbase[t] = (h > 0) ? atomicAdd(&bcur[t], h) : 0;
    __syncthreads();
    hist[t] = 0;                     // reuse as local cursor
    __syncthreads();
    #pragma unroll
    for (int k = 0; k < 16; ++k) {
        if (eb[k] >= 0) {
            int r = atomicAdd(&hist[eb[k]], 1);
            tmp[(size_t)eb[k] * CAP + rbase[eb[k]] + r] =
                make_int2(key[k], __float_as_int(ew[k]));
        }
    }
}

// -------- per-bucket fine sort: LDS counts+scan -> offs2{beg,end}, pe ----
__global__ void fine_kernel(const int2* __restrict__ tmp,
                            const int* __restrict__ bcur,
                            int2* __restrict__ offs2,
                            int2* __restrict__ pe) {
    __shared__ int cnt[BNODES];
    __shared__ int sums[256];
    int b = blockIdx.x, t = threadIdx.x;
    int nbase = b << BSHIFT;
    int ebase = b * CAP;
    int ecnt  = bcur[b];
    for (int j = t; j < BNODES; j += 256) cnt[j] = 0;
    __syncthreads();
    for (int i = t; i < ecnt; i += 256)
        atomicAdd(&cnt[((unsigned)tmp[ebase + i].x) >> 19], 1);
    __syncthreads();
    int s[8], tot = 0;
    #pragma unroll
    for (int k = 0; k < 8; ++k) { s[k] = cnt[t * 8 + k]; tot += s[k]; }
    sums[t] = tot;
    __syncthreads();
    for (int off = 1; off < 256; off <<= 1) {
        int x = (t >= off) ? sums[t - off] : 0;
        __syncthreads();
        if (t >= off) sums[t] += x;
        __syncthreads();
    }
    int run = ebase + sums[t] - tot;
    #pragma unroll
    for (int k = 0; k < 8; ++k) {
        int node = nbase + t * 8 + k;
        if (node < N_NODES) offs2[node] = make_int2(run, run + s[k]);
        cnt[t * 8 + k] = run;        // cursor
        run += s[k];
    }
    __syncthreads();
    for (int i = t; i < ecnt; i += 256) {
        int2 T = tmp[ebase + i];
        int p = atomicAdd(&cnt[((unsigned)T.x) >> 19], 1);
        pe[p] = make_int2(T.x & 0x7FFFF, T.y);
    }
}

// ------------- layer: gather bf16 -> bf16 (8 lanes/node, 8 nodes/wave) ----
__global__ void layer_kernel(const uint4* __restrict__ hsrc,
                             uint4* __restrict__ hout,
                             const int2* __restrict__ offs2,
                             const int2* __restrict__ pe) {
    int gid  = blockIdx.x * blockDim.x + threadIdx.x;
    int wave = gid >> 6;
    int lane = gid & 63;
    int grp  = lane >> 3;
    int sub  = lane & 7;
    int n    = wave * 8 + grp;
    if (n >= N_NODES) return;
    int2 oo = offs2[n];
    int beg = oo.x, end = oo.y;
    float a0[8] = {0,0,0,0,0,0,0,0};
    float a1[8] = {0,0,0,0,0,0,0,0};
    int e = beg;
    for (; e + 2 <= end; e += 2) {
        int2 p0 = pe[e], p1 = pe[e + 1];
        uint4 g0 = hsrc[(size_t)p0.x * 8 + sub];
        uint4 g1 = hsrc[(size_t)p1.x * 8 + sub];
        bf8_fma(g0, __int_as_float(p0.y), a0);
        bf8_fma(g1, __int_as_float(p1.y), a1);
    }
    if (e < end) {
        int2 p0 = pe[e];
        uint4 g0 = hsrc[(size_t)p0.x * 8 + sub];
        bf8_fma(g0, __int_as_float(p0.y), a0);
    }
    #pragma unroll
    for (int i = 0; i < 8; ++i) a0[i] += a1[i];
    uint4 r;
    r.x = bpack(a0[0], a0[1]); r.y = bpack(a0[2], a0[3]);
    r.z = bpack(a0[4], a0[5]); r.w = bpack(a0[6], a0[7]);
    hout[(size_t)n * 8 + sub] = r;
}

// final: gather h3 from h2; out = 0.25*(E + h1 + h2 + h3) (nontemporal out)
__global__ void final_kernel(const uint4* __restrict__ E,
                             const uint4* __restrict__ h1,
                             const uint4* __restrict__ h2,
                             float* __restrict__ out,
                             const int2* __restrict__ offs2,
                             const int2* __restrict__ pe) {
    int gid  = blockIdx.x * blockDim.x + threadIdx.x;
    int wave = gid >> 6;
    int lane = gid & 63;
    int grp  = lane >> 3;
    int sub  = lane & 7;
    int n    = wave * 8 + grp;
    if (n >= N_NODES) return;
    int2 oo = offs2[n];
    int beg = oo.x, end = oo.y;
    float a0[8] = {0,0,0,0,0,0,0,0};
    float a1[8] = {0,0,0,0,0,0,0,0};
    int e = beg;
    for (; e + 2 <= end; e += 2) {
        int2 p0 = pe[e], p1 = pe[e + 1];
        uint4 g0 = h2[(size_t)p0.x * 8 + sub];
        uint4 g1 = h2[(size_t)p1.x * 8 + sub];
        bf8_fma(g0, __int_as_float(p0.y), a0);
        bf8_fma(g1, __int_as_float(p1.y), a1);
    }
    if (e < end) {
        int2 p0 = pe[e];
        uint4 g0 = h2[(size_t)p0.x * 8 + sub];
        bf8_fma(g0, __int_as_float(p0.y), a0);
    }
    size_t o8 = (size_t)n * 8 + sub;
    uint4 e0 = E[o8], b1 = h1[o8], b2 = h2[o8];
    f32x4 ra, rb;
    ra.x = 0.25f * (blo(e0.x) + blo(b1.x) + blo(b2.x) + a0[0] + a1[0]);
    ra.y = 0.25f * (bhi(e0.x) + bhi(b1.x) + bhi(b2.x) + a0[1] + a1[1]);
    ra.z = 0.25f * (blo(e0.y) + blo(b1.y) + blo(b2.y) + a0[2] + a1[2]);
    ra.w = 0.25f * (bhi(e0.y) + bhi(b1.y) + bhi(b2.y) + a0[3] + a1[3]);
    rb.x = 0.25f * (blo(e0.z) + blo(b1.z) + blo(b2.z) + a0[4] + a1[4]);
    rb.y = 0.25f * (bhi(e0.z) + bhi(b1.z) + bhi(b2.z) + a0[5] + a1[5]);
    rb.z = 0.25f * (blo(e0.w) + blo(b1.w) + blo(b2.w) + a0[6] + a1[6]);
    rb.w = 0.25f * (bhi(e0.w) + bhi(b1.w) + bhi(b2.w) + a0[7] + a1[7]);
    f32x4* op = (f32x4*)out + (size_t)n * 16 + sub * 2;
    __builtin_nontemporal_store(ra, op);
    __builtin_nontemporal_store(rb, op + 1);
}

// ---------------- fallback (round-1 atomic) path ----------------
__global__ void init_fb_kernel(const float4* __restrict__ ue,
                               const float4* __restrict__ ie,
                               float4* __restrict__ h,
                               float4* __restrict__ hn,
                               float4* __restrict__ acc) {
    int i = blockIdx.x * blockDim.x + threadIdx.x;
    if (i >= NV4) return;
    const int ub = USER_NUM * EMBED_DIM / 4;
    float4 v = (i < ub) ? ue[i] : ie[i - ub];
    h[i] = v; acc[i] = v;
    hn[i] = make_float4(0.f, 0.f, 0.f, 0.f);
}

__global__ void spmm_fb_kernel(const float* __restrict__ h, float* __restrict__ hn,
                               const int* __restrict__ src, const int* __restrict__ dst,
                               const float* __restrict__ w) {
    int gid = blockIdx.x * blockDim.x + threadIdx.x;
    int wave = gid >> 6, lane = gid & 63;
    int nwave = (gridDim.x * blockDim.x) >> 6;
    for (int e = wave; e < N_EDGES; e += nwave) {
        float v = h[src[e] * 64 + lane] * w[e];
        atomicAdd(&hn[dst[e] * 64 + lane], v);
    }
}

template <int LAST>
__global__ void accum_fb_kernel(float4* __restrict__ acc, const float4* __restrict__ hn,
                                float4* __restrict__ zbuf) {
    int i = blockIdx.x * blockDim.x + threadIdx.x;
    if (i >= NV4) return;
    float4 a = acc[i], n = hn[i];
    a.x += n.x; a.y += n.y; a.z += n.z; a.w += n.w;
    if (LAST) { a.x *= 0.25f; a.y *= 0.25f; a.z *= 0.25f; a.w *= 0.25f; }
    acc[i] = a;
    if (!LAST) zbuf[i] = make_float4(0.f, 0.f, 0.f, 0.f);
}

extern "C" void kernel_launch(void* const* d_in, const int* in_sizes, int n_in,
                              void* d_out, int out_size, void* d_ws, size_t ws_size,
                              hipStream_t stream) {
    const float* ue  = (const float*)d_in[0];
    const float* ie  = (const float*)d_in[1];
    const float* w   = (const float*)d_in[2];
    const int*   src = (const int*)d_in[3];
    const int*   dst = (const int*)d_in[4];

    float* out = (float*)d_out;

    // workspace: E(64MB), B=h1(64MB), C=h2(64MB),
    //            tmp(padded int2, 16MB), pe(padded int2, 16MB),
    //            offs2(int2, 4MB), bcur(245)
    const size_t HB   = (size_t)N_NODES * 128;
    const size_t PADE = (size_t)NBUK * CAP;           // padded edge slots
    char*  base  = (char*)d_ws;
    uint4* E     = (uint4*)base;
    uint4* B     = (uint4*)(base + HB);
    uint4* C     = (uint4*)(base + 2 * HB);
    int2*  tmp   = (int2*)(base + 3 * HB);
    int2*  pe    = (int2*)(base + 3 * HB + PADE * 8);
    int2*  offs2 = (int2*)(base + 3 * HB + 2 * PADE * 8);
    int*   bcur  = (int*)(base + 3 * HB + 2 * PADE * 8 + (size_t)N_NODES * 8);

    const size_t needed = 3 * HB + 2 * PADE * 8 + (size_t)N_NODES * 8
                        + (size_t)NBUK * 4;

    const int TB = 256;
    const int egrid = NV4 / TB;
    const int fgrid = (N_NODES / 8 * 64) / TB;        // 15625 (8 nodes/wave)

    if (ws_size >= needed) {
        hipMemsetAsync(bcur, 0, (size_t)NBUK * 4, stream);
        pre_kernel<<<PGRID + CONVG, TB, 0, stream>>>(src, dst, w, bcur, tmp,
                                                     (const float4*)ue,
                                                     (const float4*)ie, E);
        fine_kernel<<<NBUK, TB, 0, stream>>>(tmp, bcur, offs2, pe);

        layer_kernel<<<fgrid, TB, 0, stream>>>(E, B, offs2, pe);   // h1
        layer_kernel<<<fgrid, TB, 0, stream>>>(B, C, offs2, pe);   // h2
        final_kernel<<<fgrid, TB, 0, stream>>>(E, B, C, out, offs2, pe);
    } else {
        // ---- fallback: atomic path ----
        float* A  = (float*)d_ws;
        float* Bf = A + NV;
        const int sgrid = 4096;
        init_fb_kernel<<<egrid, TB, 0, stream>>>((const float4*)ue, (const float4*)ie,
                                                 (float4*)A, (float4*)Bf, (float4*)out);
        spmm_fb_kernel<<<sgrid, TB, 0, stream>>>(A, Bf, src, dst, w);
        accum_fb_kernel<0><<<egrid, TB, 0, stream>>>((float4*)out, (const float4*)Bf, (float4*)A);
        spmm_fb_kernel<<<sgrid, TB, 0, stream>>>(Bf, A, src, dst, w);
        accum_fb_kernel<0><<<egrid, TB, 0, stream>>>((float4*)out, (const float4*)A, (float4*)Bf);
        spmm_fb_kernel<<<sgrid, TB, 0, stream>>>(A, Bf, src, dst, w);
        accum_fb_kernel<1><<<egrid, TB, 0, stream>>>((float4*)out, (const float4*)Bf, nullptr);
    }
}

// Round 9
// 212.816 us; speedup vs baseline: 1.2010x; 1.0266x over previous
//
#include <hip/hip_runtime.h>

// LightGCN via running sums: S1 = E + A·E, S2 = E + A·S1, out = 0.25(E + A·S2)
//  == 0.25(h0+h1+h2+h3). Removes final's h1/h2 stream reads (192->64 MB).
// bf16 storage, f32 accumulate. CSR-by-dst via capacity-padded partition.
// Bijective XCD swizzle on node-parallel kernels for per-XCD L2 locality.

#define USER_NUM  300000
#define ITEM_NUM  200000
#define N_NODES   500000
#define EMBED_DIM 64
#define NV   (N_NODES * EMBED_DIM)
#define NV4  (NV / 4)
#define N_EDGES   1250000

#define BSHIFT  11
#define BNODES  2048                               // nodes per coarse bucket
#define NBUK    ((N_NODES + BNODES - 1) / BNODES)  // 245
#define CAP     8192                               // padded slots per bucket
#define PCHUNK  4096                               // edges per partition block
#define PGRID   ((N_EDGES + PCHUNK - 1) / PCHUNK)  // 306
#define CONVG   ((N_NODES * 8) / 256)              // 15625 conv blocks

typedef float f32x4 __attribute__((ext_vector_type(4)));

// ---------------- bf16 helpers (storage only; math in f32) ----------------
__device__ __forceinline__ unsigned bpack(float lo, float hi) {
    unsigned a = __float_as_uint(lo), b = __float_as_uint(hi);
    a = (a + 0x7fffu + ((a >> 16) & 1u)) >> 16;          // RN-to-even
    b = (b + 0x7fffu + ((b >> 16) & 1u)) & 0xffff0000u;
    return a | b;
}
__device__ __forceinline__ float blo(unsigned u) { return __uint_as_float(u << 16); }
__device__ __forceinline__ float bhi(unsigned u) { return __uint_as_float(u & 0xffff0000u); }

__device__ __forceinline__ void bf8_fma(uint4 g, float w, float* a) {
    a[0] += w * blo(g.x); a[1] += w * bhi(g.x);
    a[2] += w * blo(g.y); a[3] += w * bhi(g.y);
    a[4] += w * blo(g.z); a[5] += w * bhi(g.z);
    a[6] += w * blo(g.w); a[7] += w * bhi(g.w);
}

// bijective XCD swizzle: consecutive blockIdx round-robin across 8 XCDs ->
// give each XCD a contiguous chunk of the node range (m204 formula)
__device__ __forceinline__ int swz_block(int bid, int nwg) {
    int q = nwg >> 3, r = nwg & 7;
    int x = bid & 7, i = bid >> 3;
    return (x < r ? x * (q + 1) : r * (q + 1) + (x - r) * q) + i;
}

// -------- fused pre-pass: blocks [0,PGRID) partition edges into padded
// buckets; blocks [PGRID, PGRID+CONVG) convert f32 emb -> bf16 E ----------
__global__ void pre_kernel(const int* __restrict__ src,
                           const int* __restrict__ dst,
                           const float* __restrict__ w,
                           int* __restrict__ bcur,
                           int2* __restrict__ tmp,
                           const float4* __restrict__ ue,
                           const float4* __restrict__ ie,
                           uint4* __restrict__ E) {
    __shared__ int hist[256];
    __shared__ int rbase[256];
    int t = threadIdx.x;
    if (blockIdx.x >= PGRID) {
        int i = (blockIdx.x - PGRID) * 256 + t;          // [0, N_NODES*8)
        int n = i >> 3, sub = i & 7;
        const f32x4* p = (const f32x4*)((n < USER_NUM) ? &ue[(size_t)n * 16]
                                                       : &ie[(size_t)(n - USER_NUM) * 16]);
        f32x4 a = __builtin_nontemporal_load(&p[sub * 2]);
        f32x4 b = __builtin_nontemporal_load(&p[sub * 2 + 1]);
        uint4 r;
        r.x = bpack(a.x, a.y); r.y = bpack(a.z, a.w);
        r.z = bpack(b.x, b.y); r.w = bpack(b.z, b.w);
        E[i] = r;
        return;
    }
    int cbase = blockIdx.x * PCHUNK;
    int cnt = min(PCHUNK, N_EDGES - cbase);
    int key[16], eb[16];
    float ew[16];
    hist[t] = 0;
    __syncthreads();
    #pragma unroll
    for (int k = 0; k < 16; ++k) {
        int i = t + k * 256;
        if (i < cnt) {
            int e = cbase + i;
            int d = dst[e];
            eb[k]  = d >> BSHIFT;
            key[k] = ((d & (BNODES - 1)) << 19) | src[e];   // src < 2^19
            ew[k]  = w[e];
            atomicAdd(&hist[eb[k]], 1);
        } else eb[k] = -1;
    }
    __syncthreads();
    int h = hist[t];
    rbase[t] = (h > 0) ? atomicAdd(&bcur[t], h) : 0;
    __syncthreads();
    hist[t] = 0;                     // reuse as local cursor
    __syncthreads();
    #pragma unroll
    for (int k = 0; k < 16; ++k) {
        if (eb[k] >= 0) {
            int r = atomicAdd(&hist[eb[k]], 1);
            tmp[(size_t)eb[k] * CAP + rbase[eb[k]] + r] =
                make_int2(key[k], __float_as_int(ew[k]));
        }
    }
}

// -------- per-bucket fine sort: LDS counts+scan -> offs2{beg,end}, pe ----
__global__ void fine_kernel(const int2* __restrict__ tmp,
                            const int* __restrict__ bcur,
                            int2* __restrict__ offs2,
                            int2* __restrict__ pe) {
    __shared__ int cnt[BNODES];
    __shared__ int sums[256];
    int b = blockIdx.x, t = threadIdx.x;
    int nbase = b << BSHIFT;
    int ebase = b * CAP;
    int ecnt  = bcur[b];
    for (int j = t; j < BNODES; j += 256) cnt[j] = 0;
    __syncthreads();
    for (int i = t; i < ecnt; i += 256)
        atomicAdd(&cnt[((unsigned)tmp[ebase + i].x) >> 19], 1);
    __syncthreads();
    int s[8], tot = 0;
    #pragma unroll
    for (int k = 0; k < 8; ++k) { s[k] = cnt[t * 8 + k]; tot += s[k]; }
    sums[t] = tot;
    __syncthreads();
    for (int off = 1; off < 256; off <<= 1) {
        int x = (t >= off) ? sums[t - off] : 0;
        __syncthreads();
        if (t >= off) sums[t] += x;
        __syncthreads();
    }
    int run = ebase + sums[t] - tot;
    #pragma unroll
    for (int k = 0; k < 8; ++k) {
        int node = nbase + t * 8 + k;
        if (node < N_NODES) offs2[node] = make_int2(run, run + s[k]);
        cnt[t * 8 + k] = run;        // cursor
        run += s[k];
    }
    __syncthreads();
    for (int i = t; i < ecnt; i += 256) {
        int2 T = tmp[ebase + i];
        int p = atomicAdd(&cnt[((unsigned)T.x) >> 19], 1);
        pe[p] = make_int2(T.x & 0x7FFFF, T.y);
    }
}

// ---- running-sum layer: hout[n] = bf16( E[n] + sum w * hsrc[src] ) ------
__global__ void slayer_kernel(const uint4* __restrict__ hsrc,
                              const uint4* __restrict__ E,
                              uint4* __restrict__ hout,
                              const int2* __restrict__ offs2,
                              const int2* __restrict__ pe) {
    int blk  = swz_block(blockIdx.x, gridDim.x);
    int gid  = blk * 256 + threadIdx.x;
    int wave = gid >> 6;
    int lane = gid & 63;
    int grp  = lane >> 3;
    int sub  = lane & 7;
    int n    = wave * 8 + grp;
    if (n >= N_NODES) return;
    int2 oo = offs2[n];
    int beg = oo.x, end = oo.y;
    float a0[8] = {0,0,0,0,0,0,0,0};
    float a1[8] = {0,0,0,0,0,0,0,0};
    int e = beg;
    for (; e + 2 <= end; e += 2) {
        int2 p0 = pe[e], p1 = pe[e + 1];
        uint4 g0 = hsrc[(size_t)p0.x * 8 + sub];
        uint4 g1 = hsrc[(size_t)p1.x * 8 + sub];
        bf8_fma(g0, __int_as_float(p0.y), a0);
        bf8_fma(g1, __int_as_float(p1.y), a1);
    }
    if (e < end) {
        int2 p0 = pe[e];
        uint4 g0 = hsrc[(size_t)p0.x * 8 + sub];
        bf8_fma(g0, __int_as_float(p0.y), a0);
    }
    size_t o8 = (size_t)n * 8 + sub;
    uint4 e0 = E[o8];
    a0[0] += a1[0] + blo(e0.x); a0[1] += a1[1] + bhi(e0.x);
    a0[2] += a1[2] + blo(e0.y); a0[3] += a1[3] + bhi(e0.y);
    a0[4] += a1[4] + blo(e0.z); a0[5] += a1[5] + bhi(e0.z);
    a0[6] += a1[6] + blo(e0.w); a0[7] += a1[7] + bhi(e0.w);
    uint4 r;
    r.x = bpack(a0[0], a0[1]); r.y = bpack(a0[2], a0[3]);
    r.z = bpack(a0[4], a0[5]); r.w = bpack(a0[6], a0[7]);
    hout[o8] = r;
}

// final: out = 0.25 * ( E[n] + sum w * S2[src] ), f32 nontemporal out
__global__ void final_kernel(const uint4* __restrict__ E,
                             const uint4* __restrict__ S2,
                             float* __restrict__ out,
                             const int2* __restrict__ offs2,
                             const int2* __restrict__ pe) {
    int blk  = swz_block(blockIdx.x, gridDim.x);
    int gid  = blk * 256 + threadIdx.x;
    int wave = gid >> 6;
    int lane = gid & 63;
    int grp  = lane >> 3;
    int sub  = lane & 7;
    int n    = wave * 8 + grp;
    if (n >= N_NODES) return;
    int2 oo = offs2[n];
    int beg = oo.x, end = oo.y;
    float a0[8] = {0,0,0,0,0,0,0,0};
    float a1[8] = {0,0,0,0,0,0,0,0};
    int e = beg;
    for (; e + 2 <= end; e += 2) {
        int2 p0 = pe[e], p1 = pe[e + 1];
        uint4 g0 = S2[(size_t)p0.x * 8 + sub];
        uint4 g1 = S2[(size_t)p1.x * 8 + sub];
        bf8_fma(g0, __int_as_float(p0.y), a0);
        bf8_fma(g1, __int_as_float(p1.y), a1);
    }
    if (e < end) {
        int2 p0 = pe[e];
        uint4 g0 = S2[(size_t)p0.x * 8 + sub];
        bf8_fma(g0, __int_as_float(p0.y), a0);
    }
    size_t o8 = (size_t)n * 8 + sub;
    uint4 e0 = E[o8];
    f32x4 ra, rb;
    ra.x = 0.25f * (blo(e0.x) + a0[0] + a1[0]);
    ra.y = 0.25f * (bhi(e0.x) + a0[1] + a1[1]);
    ra.z = 0.25f * (blo(e0.y) + a0[2] + a1[2]);
    ra.w = 0.25f * (bhi(e0.y) + a0[3] + a1[3]);
    rb.x = 0.25f * (blo(e0.z) + a0[4] + a1[4]);
    rb.y = 0.25f * (bhi(e0.z) + a0[5] + a1[5]);
    rb.z = 0.25f * (blo(e0.w) + a0[6] + a1[6]);
    rb.w = 0.25f * (bhi(e0.w) + a0[7] + a1[7]);
    f32x4* op = (f32x4*)out + (size_t)n * 16 + sub * 2;
    __builtin_nontemporal_store(ra, op);
    __builtin_nontemporal_store(rb, op + 1);
}

// ---------------- fallback (round-1 atomic) path ----------------
__global__ void init_fb_kernel(const float4* __restrict__ ue,
                               const float4* __restrict__ ie,
                               float4* __restrict__ h,
                               float4* __restrict__ hn,
                               float4* __restrict__ acc) {
    int i = blockIdx.x * blockDim.x + threadIdx.x;
    if (i >= NV4) return;
    const int ub = USER_NUM * EMBED_DIM / 4;
    float4 v = (i < ub) ? ue[i] : ie[i - ub];
    h[i] = v; acc[i] = v;
    hn[i] = make_float4(0.f, 0.f, 0.f, 0.f);
}

__global__ void spmm_fb_kernel(const float* __restrict__ h, float* __restrict__ hn,
                               const int* __restrict__ src, const int* __restrict__ dst,
                               const float* __restrict__ w) {
    int gid = blockIdx.x * blockDim.x + threadIdx.x;
    int wave = gid >> 6, lane = gid & 63;
    int nwave = (gridDim.x * blockDim.x) >> 6;
    for (int e = wave; e < N_EDGES; e += nwave) {
        float v = h[src[e] * 64 + lane] * w[e];
        atomicAdd(&hn[dst[e] * 64 + lane], v);
    }
}

template <int LAST>
__global__ void accum_fb_kernel(float4* __restrict__ acc, const float4* __restrict__ hn,
                                float4* __restrict__ zbuf) {
    int i = blockIdx.x * blockDim.x + threadIdx.x;
    if (i >= NV4) return;
    float4 a = acc[i], n = hn[i];
    a.x += n.x; a.y += n.y; a.z += n.z; a.w += n.w;
    if (LAST) { a.x *= 0.25f; a.y *= 0.25f; a.z *= 0.25f; a.w *= 0.25f; }
    acc[i] = a;
    if (!LAST) zbuf[i] = make_float4(0.f, 0.f, 0.f, 0.f);
}

extern "C" void kernel_launch(void* const* d_in, const int* in_sizes, int n_in,
                              void* d_out, int out_size, void* d_ws, size_t ws_size,
                              hipStream_t stream) {
    const float* ue  = (const float*)d_in[0];
    const float* ie  = (const float*)d_in[1];
    const float* w   = (const float*)d_in[2];
    const int*   src = (const int*)d_in[3];
    const int*   dst = (const int*)d_in[4];

    float* out = (float*)d_out;

    // workspace: E(64MB), S1(64MB), S2(64MB),
    //            tmp(padded int2 16MB), pe(padded int2 16MB),
    //            offs2(int2 4MB), bcur(245)
    const size_t HB   = (size_t)N_NODES * 128;
    const size_t PADE = (size_t)NBUK * CAP;
    char*  base  = (char*)d_ws;
    uint4* E     = (uint4*)base;
    uint4* S1    = (uint4*)(base + HB);
    uint4* S2    = (uint4*)(base + 2 * HB);
    int2*  tmp   = (int2*)(base + 3 * HB);
    int2*  pe    = (int2*)(base + 3 * HB + PADE * 8);
    int2*  offs2 = (int2*)(base + 3 * HB + 2 * PADE * 8);
    int*   bcur  = (int*)(base + 3 * HB + 2 * PADE * 8 + (size_t)N_NODES * 8);

    const size_t needed = 3 * HB + 2 * PADE * 8 + (size_t)N_NODES * 8
                        + (size_t)NBUK * 4;

    const int TB = 256;
    const int egrid = NV4 / TB;
    const int fgrid = (N_NODES / 8 * 64) / TB;        // 15625 (8 nodes/wave)

    if (ws_size >= needed) {
        hipMemsetAsync(bcur, 0, (size_t)NBUK * 4, stream);
        pre_kernel<<<PGRID + CONVG, TB, 0, stream>>>(src, dst, w, bcur, tmp,
                                                     (const float4*)ue,
                                                     (const float4*)ie, E);
        fine_kernel<<<NBUK, TB, 0, stream>>>(tmp, bcur, offs2, pe);

        slayer_kernel<<<fgrid, TB, 0, stream>>>(E,  E, S1, offs2, pe);  // S1=E+A·E
        slayer_kernel<<<fgrid, TB, 0, stream>>>(S1, E, S2, offs2, pe);  // S2=E+A·S1
        final_kernel<<<fgrid, TB, 0, stream>>>(E, S2, out, offs2, pe);  // 0.25(E+A·S2)
    } else {
        // ---- fallback: atomic path ----
        float* A  = (float*)d_ws;
        float* Bf = A + NV;
        const int sgrid = 4096;
        init_fb_kernel<<<egrid, TB, 0, stream>>>((const float4*)ue, (const float4*)ie,
                                                 (float4*)A, (float4*)Bf, (float4*)out);
        spmm_fb_kernel<<<sgrid, TB, 0, stream>>>(A, Bf, src, dst, w);
        accum_fb_kernel<0><<<egrid, TB, 0, stream>>>((float4*)out, (const float4*)Bf, (float4*)A);
        spmm_fb_kernel<<<sgrid, TB, 0, stream>>>(Bf, A, src, dst, w);
        accum_fb_kernel<0><<<egrid, TB, 0, stream>>>((float4*)out, (const float4*)A, (float4*)Bf);
        spmm_fb_kernel<<<sgrid, TB, 0, stream>>>(A, Bf, src, dst, w);
        accum_fb_kernel<1><<<egrid, TB, 0, stream>>>((float4*)out, (const float4*)Bf, nullptr);
    }
}